// Round 1
// baseline (1051.736 us; speedup 1.0000x reference)
//
#include <hip/hip_runtime.h>
#include <math.h>

#define CIN   16
#define DDEP  8      // conv depth (routing "D")
#define HIN   96
#define WIN   96
#define HOUT  94
#define WOUT  94
#define HW    (HOUT*WOUT)        // 8836
#define CH    256                 // out channels = c*8+d
#define DCAP  8
#define KTOT  (CIN*9)             // 144
#define KTILES 5                  // K padded to 160
#define APAD  168                 // A row stride (bf16 elems)
#define EPSQ  1e-8f

#define B_ELEMS ((size_t)8*DDEP*DCAP*HW)          // 4,524,032 floats
#define WFRAG_ELEMS ((size_t)KTILES*16*64*8)      // 40,960 per half
#define NBLK    ((size_t)12*94*8)                 // 9024 blocks
#define U_BYTES (NBLK*64*256*4)                   // 591,396,864 B

typedef __attribute__((ext_vector_type(8))) short bf16x8;
typedef __attribute__((ext_vector_type(4))) float f32x4;

// explicit RNE float->bf16 bit conversion
__device__ __forceinline__ ushort f2bf(float f) {
    unsigned u = __float_as_uint(f);
    return (ushort)((u + 0x7FFFu + ((u >> 16) & 1u)) >> 16);
}
__device__ __forceinline__ float bf2f(ushort h) {
    return __uint_as_float(((unsigned)h) << 16);
}

// ---------------------------------------------------------------------------
// W -> MFMA B-fragment order, hi/lo split. frag[kt][nt][lane][j] = W[k][n],
// k = kt*32 + (lane>>4)*8 + j (0 for k>=144), n = nt*16 + (lane&15).
// r10: also zeroes Z[0..127] (Z1 for iter1 softmax, Z2 for iter2) so the
// conv/route epilogues can accumulate Z via device-scope atomics.
// ---------------------------------------------------------------------------
__global__ __launch_bounds__(64) void build_wfrag(
    const float* __restrict__ w, ushort* __restrict__ w_hi, ushort* __restrict__ w_lo,
    float* __restrict__ Z)
{
    const int lane = threadIdx.x;
    if (blockIdx.x == 0 && blockIdx.y == 0) { Z[lane] = 0.f; Z[64 + lane] = 0.f; }
    const int nt = blockIdx.x, kt = blockIdx.y;
    const int n  = nt*16 + (lane & 15);
    const int kb = kt*32 + (lane >> 4)*8;
    size_t off = (((size_t)kt*16 + nt)*64 + lane)*8;
    for (int j = 0; j < 8; ++j) {
        int k = kb + j;
        float v = (k < KTOT) ? w[(size_t)n*KTOT + k] : 0.f;
        ushort hi = f2bf(v);
        float  r  = v - bf2f(hi);
        ushort lo = f2bf(r);
        w_hi[off + j] = hi; w_lo[off + j] = lo;
    }
}

// ---------------------------------------------------------------------------
// Shared routing epilogue (phase 3). acc[mt][nt][r]:
//   m = mt*16 + quad*4 + r -> D = mt*2 + (quad>>1), wi = (quad&1)*4 + r;
//   ch = wv*64 + nt*16 + m16; d = m16&7.
// MODE 0: iter1 (uniform c), writes b, accumulates Z1 = sum exp(b1).
// MODE 1: iter2, b += db, accumulates Z2 = sum exp(b2).
// MODE 2: writes s.
// NOTE (r7): epilogue verified element-exact; keep the math/order unchanged.
// r10: Z accumulation fused here (replaces softmax_z kernels). Z layout:
// Z[0..63] = Z1, Z[64..127] = Z2; zeroed by build_wfrag; device-scope atomics.
// ---------------------------------------------------------------------------
template<int MODE>
__device__ __forceinline__ void routing_epilogue(
    const f32x4 (&acc)[4][4], const int t, const int w0, const int h0, const int bb,
    const float (*cms)[8], const float* invZ,
    float (*n2s)[8][8], float (*dbs)[8][8][8], float (*sout)[8],
    float* __restrict__ bws, float* __restrict__ Z, float* __restrict__ out)
{
    const int wv = t >> 6, lane = t & 63;
    const int m16 = lane & 15, quad = lane >> 4;
    const int d   = m16 & 7;
    const int Dq  = quad >> 1;      // D parity bit (lane bit5)
    const int wih = quad & 1;       // wi half (lane bit4)

    // sv[nt][r] = sum_D cm(D,d,wi)*u(D,...): reg-sum over mt + shfl_xor(32)
    float svv[4][4];
    {
        float cmw[4][4];
        if (MODE == 0) {
            const float inv = 1.0f / (float)(DCAP * HW);
            #pragma unroll
            for (int mt = 0; mt < 4; ++mt)
                #pragma unroll
                for (int r = 0; r < 4; ++r) cmw[mt][r] = inv;
        } else {
            #pragma unroll
            for (int mt = 0; mt < 4; ++mt) {
                int D = mt*2 + Dq;
                float iz = invZ[D];
                #pragma unroll
                for (int r = 0; r < 4; ++r) cmw[mt][r] = cms[D*8 + d][wih*4 + r] * iz;
            }
        }
        #pragma unroll
        for (int nt = 0; nt < 4; ++nt)
            #pragma unroll
            for (int r = 0; r < 4; ++r) {
                float partial = 0.f;
                #pragma unroll
                for (int mt = 0; mt < 4; ++mt) partial += cmw[mt][r]*acc[mt][nt][r];
                partial += __shfl_xor(partial, 32);
                svv[nt][r] = partial;   // uniform in lane bit5
            }
    }

    if (MODE == 2) {
        if (quad < 2) {   // one Dq copy per (wih, m16, nt)
            #pragma unroll
            for (int nt = 0; nt < 4; ++nt) {
                int ch = wv*64 + nt*16 + m16;
                #pragma unroll
                for (int r = 0; r < 4; ++r) sout[ch][wih*4 + r] = svv[nt][r];
            }
        }
        __syncthreads();
        for (int i = t; i < 1024; i += 256) {
            int c2 = i >> 2, wip = i & 3;
            int w = w0 + wip*2;
            if (w + 1 < WOUT) {
                float2 v2 = { sout[c2][wip*2], sout[c2][wip*2 + 1] };
                *(float2*)&out[((size_t)bb*CH + c2)*HW + (size_t)h0*WOUT + w] = v2;
            }
        }
        return;
    }

    // n2(d,wi) = sum_c sv^2 : reg-sum over nt + shfl_xor(8) + cross-wave LDS
    float p2[4];
    #pragma unroll
    for (int r = 0; r < 4; ++r) {
        float s2 = 0.f;
        #pragma unroll
        for (int nt = 0; nt < 4; ++nt) s2 += svv[nt][r]*svv[nt][r];
        p2[r] = s2;
    }
    #pragma unroll
    for (int r = 0; r < 4; ++r) p2[r] += __shfl_xor(p2[r], 8);
    if (quad < 2 && m16 < 8) {
        #pragma unroll
        for (int r = 0; r < 4; ++r) n2s[wv][m16][quad*4 + r] = p2[r];
    }
    __syncthreads();
    float fac[4];
    #pragma unroll
    for (int r = 0; r < 4; ++r) {
        int wi = wih*4 + r;
        float n2 = n2s[0][d][wi] + n2s[1][d][wi] + n2s[2][d][wi] + n2s[3][d][wi];
        fac[r] = (n2 / (1.f + n2)) / sqrtf(n2 + EPSQ);
    }
    // db(D,d,wi) = sum_c u*v : reg-sum over nt + shfl_xor(8) + cross-wave LDS
    float qv[4][4];
    #pragma unroll
    for (int mt = 0; mt < 4; ++mt)
        #pragma unroll
        for (int r = 0; r < 4; ++r) {
            float sum = 0.f;
            #pragma unroll
            for (int nt = 0; nt < 4; ++nt)
                sum += acc[mt][nt][r] * (svv[nt][r] * fac[r]);
            qv[mt][r] = sum;
        }
    #pragma unroll
    for (int mt = 0; mt < 4; ++mt)
        #pragma unroll
        for (int r = 0; r < 4; ++r) qv[mt][r] += __shfl_xor(qv[mt][r], 8);
    if (m16 < 8) {
        #pragma unroll
        for (int mt = 0; mt < 4; ++mt) {
            int D = mt*2 + Dq;
            #pragma unroll
            for (int r = 0; r < 4; ++r) dbs[wv][D][m16][wih*4 + r] = qv[mt][r];
        }
    }
    __syncthreads();
    // b write: 64 (D,d) x 8 wi, float2 runs + fused Z accumulation
    {
        int Dd = t >> 2, wip = t & 3;
        int D = Dd >> 3, d2 = Dd & 7;   // D = t>>5, uniform per 32-lane group
        int w = w0 + wip*2;
        float ez = 0.f;
        if (w + 1 < WOUT) {
            int wi = wip*2;
            float2 add;
            add.x = dbs[0][D][d2][wi]   + dbs[1][D][d2][wi]
                  + dbs[2][D][d2][wi]   + dbs[3][D][d2][wi];
            add.y = dbs[0][D][d2][wi+1] + dbs[1][D][d2][wi+1]
                  + dbs[2][D][d2][wi+1] + dbs[3][D][d2][wi+1];
            float2* bp = (float2*)&bws[((size_t)bb*64 + Dd)*HW + (size_t)h0*WOUT + w];
            if (MODE != 0) { float2 old = *bp; add.x += old.x; add.y += old.y; }
            *bp = add;
            ez = expf(add.x) + expf(add.y);   // same values later read as cms
        }
        #pragma unroll
        for (int off = 1; off < 32; off <<= 1) ez += __shfl_xor(ez, off);
        if ((t & 31) == 0) atomicAdd(&Z[(MODE == 0 ? 0 : 64) + bb*8 + D], ez);
    }
}

// ---------------------------------------------------------------------------
// Implicit-GEMM MFMA conv + fused routing.
// Block: (wx,h0,bb) -> 1 batch x 8 D x 1 h-row x 8 consecutive w; M=64, N=256.
// NOTE (r7): MFMA + in-register epilogue verified element-exact vs fp32.
// Do NOT reintroduce an LDS u_tile round-trip (rounds 4-6 corruption).
// r9: spatial 1x8 tiling for HBM line efficiency.
// r10: (a) WU=true stores acc (u) to workspace in per-wave fragment order so
//      iters 2/3 become streaming epilogue kernels (route_from_u);
//      (b) patch LDS overlaid (union) with epilogue arrays — patch is dead
//      after the phase-1 barrier, epilogue arrays first written post-MFMA;
//      (c) Z accumulated in epilogue (softmax_z removed).
// ---------------------------------------------------------------------------
template<int MODE, bool WU>
__global__ __launch_bounds__(256, 2) void conv_mfma_route(
    const float* __restrict__ x,
    const ushort* __restrict__ w_hi, const ushort* __restrict__ w_lo,
    float* __restrict__ bws, float* __restrict__ Z,
    float* __restrict__ out, float* __restrict__ u_ws)
{
    const int t  = threadIdx.x;
    const int wx = blockIdx.x, h0 = blockIdx.y, bb = blockIdx.z;
    const int w0 = wx*8;

    __shared__ ushort a_hi[64][APAD];            // 21504 B (persists all phases)
    __shared__ float  cms[64][8];                // 2048 B (phase0 -> epilogue)
    __shared__ float  invZ[8];
    __shared__ union {                           // 15360 B, lifetime-disjoint:
        float patch[CIN][DDEP][3][10];           //   phases 0-1 only
        struct { float n2s[4][8][8];             //   epilogue (MODE 0/1)
                 float dbs[4][8][8][8]; } ep;
        float sout[256][8];                      //   epilogue (MODE 2)
    } ov;

    // ---- phase 0: stage c-coeffs + x patch ----
    if (MODE != 0) {
        if (t < 8) invZ[t] = 1.0f / Z[(MODE == 2 ? 64 : 0) + bb*8 + t];
        for (int v = t; v < 512; v += 256) {
            int Dd = v >> 3, wi = v & 7;
            int w = w0 + wi;
            float bv = (w < WOUT) ? bws[((size_t)bb*64 + Dd)*HW + (size_t)h0*WOUT + w] : 0.f;
            cms[Dd][wi] = expf(bv);
        }
    }
    for (int i = t; i < CIN*DDEP*3*10; i += 256) {
        int ci = i / 240, rem = i - ci*240;
        int D  = rem / 30, rem2 = rem - D*30;
        int kh = rem2 / 10, col = rem2 - kh*10;
        int xc = w0 + col; if (xc > 95) xc = 95;   // clamp: garbage feeds only invalid sites
        ov.patch[ci][D][kh][col] =
            x[(((size_t)(bb*CIN + ci)*DDEP + D)*HIN + (h0+kh))*WIN + xc];
    }
    __syncthreads();

    // ---- phase 1: im2col -> bf16 A (uint stores; thread = site x kgroup) ----
    {
        const int site = t >> 2, kg = t & 3;     // site = D*8 + wi
        const int D = site >> 3, wi = site & 7;
        #pragma unroll
        for (int u2 = 0; u2 < 18; ++u2) {
            int k0 = kg*36 + u2*2;
            int ci0 = k0/9, r0 = k0 - ci0*9, kh0 = r0/3, kw0 = r0 - kh0*3;
            int k1 = k0 + 1;
            int ci1 = k1/9, r1 = k1 - ci1*9, kh1 = r1/3, kw1 = r1 - kh1*3;
            unsigned lo = f2bf(ov.patch[ci0][D][kh0][wi+kw0]);
            unsigned hi = f2bf(ov.patch[ci1][D][kh1][wi+kw1]);
            *(unsigned*)&a_hi[site][k0] = lo | (hi << 16);
        }
        if (t < 64) {
            #pragma unroll
            for (int kk = KTOT; kk < KTILES*32; kk += 2)
                *(unsigned*)&a_hi[t][kk] = 0u;
        }
    }
    __syncthreads();

    // ---- phase 2: MFMA K-loop ----
    const int wv = t >> 6, lane = t & 63;
    const int m16 = lane & 15, quad = lane >> 4;
    f32x4 acc[4][4];
    #pragma unroll
    for (int mt = 0; mt < 4; ++mt)
        #pragma unroll
        for (int nt = 0; nt < 4; ++nt)
            acc[mt][nt] = (f32x4){0.f, 0.f, 0.f, 0.f};

    #pragma unroll
    for (int kt = 0; kt < KTILES; ++kt) {
        bf16x8 ah[4];
        #pragma unroll
        for (int mt = 0; mt < 4; ++mt)
            ah[mt] = *(const bf16x8*)&a_hi[mt*16 + m16][kt*32 + quad*8];
        #pragma unroll
        for (int nt = 0; nt < 4; ++nt) {
            size_t off = (((size_t)kt*16 + (wv*4 + nt))*64 + lane)*8;
            bf16x8 bh = *(const bf16x8*)&w_hi[off];
            bf16x8 bl = *(const bf16x8*)&w_lo[off];
            #pragma unroll
            for (int mt = 0; mt < 4; ++mt) {
                acc[mt][nt] = __builtin_amdgcn_mfma_f32_16x16x32_bf16(ah[mt], bh, acc[mt][nt], 0, 0, 0);
                acc[mt][nt] = __builtin_amdgcn_mfma_f32_16x16x32_bf16(ah[mt], bl, acc[mt][nt], 0, 0, 0);
            }
        }
    }

    // ---- u spill to workspace (fire-and-forget coalesced stores) ----
    if (WU) {
        f32x4* up = (f32x4*)u_ws;
        size_t ub = ((((size_t)((bb*94 + h0)*12 + wx))*4 + wv)*16)*64 + lane;
        #pragma unroll
        for (int mt = 0; mt < 4; ++mt)
            #pragma unroll
            for (int nt = 0; nt < 4; ++nt)
                up[ub + (size_t)(mt*4 + nt)*64] = acc[mt][nt];
    }

    // ---- phase 3: in-register epilogue ----
    routing_epilogue<MODE>(acc, t, w0, h0, bb, cms, invZ,
                           ov.ep.n2s, ov.ep.dbs, ov.sout, bws, Z, out);
}

// ---------------------------------------------------------------------------
// r10: routing iterations 2/3 when u is cached in workspace. Pure streaming:
// load the wave's 16 f32x4 u-fragments (64 KB/block, fully coalesced) and run
// the identical epilogue. Bitwise-identical acc values => identical numerics.
// ---------------------------------------------------------------------------
template<int MODE>
__global__ __launch_bounds__(256, 3) void route_from_u(
    const float* __restrict__ u_ws, float* __restrict__ bws,
    float* __restrict__ Z, float* __restrict__ out)
{
    const int t  = threadIdx.x;
    const int wx = blockIdx.x, h0 = blockIdx.y, bb = blockIdx.z;
    const int w0 = wx*8;

    __shared__ float cms[64][8];
    __shared__ float invZ[8];
    __shared__ union {
        struct { float n2s[4][8][8]; float dbs[4][8][8][8]; } ep;
        float sout[256][8];
    } ov;

    const int wv = t >> 6, lane = t & 63;
    f32x4 acc[4][4];
    {
        const f32x4* up = (const f32x4*)u_ws;
        size_t ub = ((((size_t)((bb*94 + h0)*12 + wx))*4 + wv)*16)*64 + lane;
        #pragma unroll
        for (int mt = 0; mt < 4; ++mt)
            #pragma unroll
            for (int nt = 0; nt < 4; ++nt)
                acc[mt][nt] = up[ub + (size_t)(mt*4 + nt)*64];
    }

    if (t < 8) invZ[t] = 1.0f / Z[(MODE == 2 ? 64 : 0) + bb*8 + t];
    for (int v = t; v < 512; v += 256) {
        int Dd = v >> 3, wi = v & 7;
        int w = w0 + wi;
        float bv = (w < WOUT) ? bws[((size_t)bb*64 + Dd)*HW + (size_t)h0*WOUT + w] : 0.f;
        cms[Dd][wi] = expf(bv);
    }
    __syncthreads();

    routing_epilogue<MODE>(acc, t, w0, h0, bb, cms, invZ,
                           ov.ep.n2s, ov.ep.dbs, ov.sout, bws, Z, out);
}

// ---------------------------------------------------------------------------
extern "C" void kernel_launch(void* const* d_in, const int* in_sizes, int n_in,
                              void* d_out, int out_size, void* d_ws, size_t ws_size,
                              hipStream_t stream)
{
    (void)in_sizes; (void)n_in; (void)out_size;
    const float* x     = (const float*)d_in[0];
    const float* wconv = (const float*)d_in[1];
    float* out = (float*)d_out;

    float*  bws  = (float*)d_ws;
    float*  Z    = bws + B_ELEMS;            // Z1 = Z[0..63], Z2 = Z[64..127]
    ushort* w_hi = (ushort*)(Z + 128);
    ushort* w_lo = w_hi + WFRAG_ELEMS;
    size_t  base = (size_t)((char*)(w_lo + WFRAG_ELEMS) - (char*)d_ws);
    size_t  uoff = (base + 255) & ~(size_t)255;
    float*  u_ws = (float*)((char*)d_ws + uoff);
    const bool big = ws_size >= uoff + U_BYTES;   // ~610 MB needed for u-cache

    build_wfrag<<<dim3(16, KTILES), 64, 0, stream>>>(wconv, w_hi, w_lo, Z);
    if (big) {
        conv_mfma_route<0, true ><<<dim3(12,94,8), 256, 0, stream>>>(x, w_hi, w_lo, bws, Z, out, u_ws);
        route_from_u<1><<<dim3(12,94,8), 256, 0, stream>>>(u_ws, bws, Z, out);
        route_from_u<2><<<dim3(12,94,8), 256, 0, stream>>>(u_ws, bws, Z, out);
    } else {
        // fallback: workspace too small to cache u — original 3-pass recompute
        conv_mfma_route<0, false><<<dim3(12,94,8), 256, 0, stream>>>(x, w_hi, w_lo, bws, Z, out, nullptr);
        conv_mfma_route<1, false><<<dim3(12,94,8), 256, 0, stream>>>(x, w_hi, w_lo, bws, Z, out, nullptr);
        conv_mfma_route<2, false><<<dim3(12,94,8), 256, 0, stream>>>(x, w_hi, w_lo, bws, Z, out, nullptr);
    }
}

// Round 2
// 595.008 us; speedup vs baseline: 1.7676x; 1.7676x over previous
//
#include <hip/hip_runtime.h>
#include <math.h>

#define CIN   16
#define DDEP  8      // conv depth (routing "D")
#define HIN   96
#define WIN   96
#define HOUT  94
#define WOUT  94
#define HW    (HOUT*WOUT)        // 8836
#define CH    256                 // out channels = c*8+d
#define DCAP  8
#define KTOT  (CIN*9)             // 144
#define KTILES 5                  // K padded to 160
#define APAD  168                 // A row stride (bf16 elems)
#define EPSQ  1e-8f

#define B_ELEMS ((size_t)8*DDEP*DCAP*HW)          // 4,524,032 floats
#define WFRAG_ELEMS ((size_t)KTILES*16*64*8)      // 40,960 per half
#define BLK_PER_B (94*12)                         // 1128 spatial blocks/batch
#define NBLK ((size_t)8*BLK_PER_B)                // 9024 blocks
#define A_TILE_BYTES ((size_t)64*APAD*2)          // 21504 B per block
#define A_TILE_V4 (A_TILE_BYTES/16)               // 1344 float4 per block
#define AC_BYTES (NBLK*A_TILE_BYTES)              // 194,052,096 B

typedef __attribute__((ext_vector_type(8))) short bf16x8;
typedef __attribute__((ext_vector_type(4))) float f32x4;

// explicit RNE float->bf16 bit conversion
__device__ __forceinline__ ushort f2bf(float f) {
    unsigned u = __float_as_uint(f);
    return (ushort)((u + 0x7FFFu + ((u >> 16) & 1u)) >> 16);
}
__device__ __forceinline__ float bf2f(ushort h) {
    return __uint_as_float(((unsigned)h) << 16);
}

// ---------------------------------------------------------------------------
// W -> MFMA B-fragment order, hi/lo split. frag[kt][nt][lane][j] = W[k][n],
// k = kt*32 + (lane>>4)*8 + j (0 for k>=144), n = nt*16 + (lane&15).
// ---------------------------------------------------------------------------
__global__ __launch_bounds__(64) void build_wfrag(
    const float* __restrict__ w, ushort* __restrict__ w_hi, ushort* __restrict__ w_lo)
{
    const int lane = threadIdx.x;
    const int nt = blockIdx.x, kt = blockIdx.y;
    const int n  = nt*16 + (lane & 15);
    const int kb = kt*32 + (lane >> 4)*8;
    size_t off = (((size_t)kt*16 + nt)*64 + lane)*8;
    for (int j = 0; j < 8; ++j) {
        int k = kb + j;
        float v = (k < KTOT) ? w[(size_t)n*KTOT + k] : 0.f;
        ushort hi = f2bf(v);
        float  r  = v - bf2f(hi);
        ushort lo = f2bf(r);
        w_hi[off + j] = hi; w_lo[off + j] = lo;
    }
}

// ---------------------------------------------------------------------------
// r11: Z reduce from contention-free per-block partials.
// Zp[(bb*8+D)*1128 + blockslot] -> Z[dst + bd]. 64 blocks, 4.5KB each, ~5us.
// (r10 lesson: 72k atomicAdds onto 8 cache lines serialized ~+120us/pass;
//  NEVER funnel per-block Z through same-address device atomics.)
// ---------------------------------------------------------------------------
__global__ __launch_bounds__(256) void zreduce(
    const float* __restrict__ Zp, float* __restrict__ Z, int dst)
{
    const int bd = blockIdx.x;
    const float* p = Zp + (size_t)bd * BLK_PER_B;
    float s = 0.f;
    for (int i = threadIdx.x; i < BLK_PER_B; i += 256) s += p[i];
    #pragma unroll
    for (int off = 1; off < 64; off <<= 1) s += __shfl_xor(s, off);
    __shared__ float ps[4];
    if ((threadIdx.x & 63) == 0) ps[threadIdx.x >> 6] = s;
    __syncthreads();
    if (threadIdx.x == 0) Z[dst + bd] = ps[0] + ps[1] + ps[2] + ps[3];
}

// ---------------------------------------------------------------------------
// Shared routing epilogue (phase 3). acc[mt][nt][r]:
//   m = mt*16 + quad*4 + r -> D = mt*2 + (quad>>1), wi = (quad&1)*4 + r;
//   ch = wv*64 + nt*16 + m16; d = m16&7.
// MODE 0: iter1 (uniform c), writes b + per-block Z1 partial.
// MODE 1: iter2, b += db, writes per-block Z2 partial.
// MODE 2: writes s.
// NOTE (r7): epilogue verified element-exact; keep the math/order unchanged.
// ---------------------------------------------------------------------------
template<int MODE>
__device__ __forceinline__ void routing_epilogue(
    const f32x4 (&acc)[4][4], const int t, const int wx, const int h0, const int bb,
    const float (*cms)[8], const float* invZ,
    float (*n2s)[8][8], float (*dbs)[8][8][8], float (*sout)[8],
    float* __restrict__ bws, float* __restrict__ Zp, float* __restrict__ out)
{
    const int w0 = wx*8;
    const int wv = t >> 6, lane = t & 63;
    const int m16 = lane & 15, quad = lane >> 4;
    const int d   = m16 & 7;
    const int Dq  = quad >> 1;      // D parity bit (lane bit5)
    const int wih = quad & 1;       // wi half (lane bit4)

    // sv[nt][r] = sum_D cm(D,d,wi)*u(D,...): reg-sum over mt + shfl_xor(32)
    float svv[4][4];
    {
        float cmw[4][4];
        if (MODE == 0) {
            const float inv = 1.0f / (float)(DCAP * HW);
            #pragma unroll
            for (int mt = 0; mt < 4; ++mt)
                #pragma unroll
                for (int r = 0; r < 4; ++r) cmw[mt][r] = inv;
        } else {
            #pragma unroll
            for (int mt = 0; mt < 4; ++mt) {
                int D = mt*2 + Dq;
                float iz = invZ[D];
                #pragma unroll
                for (int r = 0; r < 4; ++r) cmw[mt][r] = cms[D*8 + d][wih*4 + r] * iz;
            }
        }
        #pragma unroll
        for (int nt = 0; nt < 4; ++nt)
            #pragma unroll
            for (int r = 0; r < 4; ++r) {
                float partial = 0.f;
                #pragma unroll
                for (int mt = 0; mt < 4; ++mt) partial += cmw[mt][r]*acc[mt][nt][r];
                partial += __shfl_xor(partial, 32);
                svv[nt][r] = partial;   // uniform in lane bit5
            }
    }

    if (MODE == 2) {
        if (quad < 2) {   // one Dq copy per (wih, m16, nt)
            #pragma unroll
            for (int nt = 0; nt < 4; ++nt) {
                int ch = wv*64 + nt*16 + m16;
                #pragma unroll
                for (int r = 0; r < 4; ++r) sout[ch][wih*4 + r] = svv[nt][r];
            }
        }
        __syncthreads();
        for (int i = t; i < 1024; i += 256) {
            int c2 = i >> 2, wip = i & 3;
            int w = w0 + wip*2;
            if (w + 1 < WOUT) {
                float2 v2 = { sout[c2][wip*2], sout[c2][wip*2 + 1] };
                *(float2*)&out[((size_t)bb*CH + c2)*HW + (size_t)h0*WOUT + w] = v2;
            }
        }
        return;
    }

    // n2(d,wi) = sum_c sv^2 : reg-sum over nt + shfl_xor(8) + cross-wave LDS
    float p2[4];
    #pragma unroll
    for (int r = 0; r < 4; ++r) {
        float s2 = 0.f;
        #pragma unroll
        for (int nt = 0; nt < 4; ++nt) s2 += svv[nt][r]*svv[nt][r];
        p2[r] = s2;
    }
    #pragma unroll
    for (int r = 0; r < 4; ++r) p2[r] += __shfl_xor(p2[r], 8);
    if (quad < 2 && m16 < 8) {
        #pragma unroll
        for (int r = 0; r < 4; ++r) n2s[wv][m16][quad*4 + r] = p2[r];
    }
    __syncthreads();
    float fac[4];
    #pragma unroll
    for (int r = 0; r < 4; ++r) {
        int wi = wih*4 + r;
        float n2 = n2s[0][d][wi] + n2s[1][d][wi] + n2s[2][d][wi] + n2s[3][d][wi];
        fac[r] = (n2 / (1.f + n2)) / sqrtf(n2 + EPSQ);
    }
    // db(D,d,wi) = sum_c u*v : reg-sum over nt + shfl_xor(8) + cross-wave LDS
    float qv[4][4];
    #pragma unroll
    for (int mt = 0; mt < 4; ++mt)
        #pragma unroll
        for (int r = 0; r < 4; ++r) {
            float sum = 0.f;
            #pragma unroll
            for (int nt = 0; nt < 4; ++nt)
                sum += acc[mt][nt][r] * (svv[nt][r] * fac[r]);
            qv[mt][r] = sum;
        }
    #pragma unroll
    for (int mt = 0; mt < 4; ++mt)
        #pragma unroll
        for (int r = 0; r < 4; ++r) qv[mt][r] += __shfl_xor(qv[mt][r], 8);
    if (m16 < 8) {
        #pragma unroll
        for (int mt = 0; mt < 4; ++mt) {
            int D = mt*2 + Dq;
            #pragma unroll
            for (int r = 0; r < 4; ++r) dbs[wv][D][m16][wih*4 + r] = qv[mt][r];
        }
    }
    __syncthreads();
    // b write: 64 (D,d) x 8 wi, float2 runs + per-block Z partial
    {
        int Dd = t >> 2, wip = t & 3;
        int D = Dd >> 3, d2 = Dd & 7;   // D = t>>5, uniform per 32-lane group
        int w = w0 + wip*2;
        float ez = 0.f;
        if (w + 1 < WOUT) {
            int wi = wip*2;
            float2 add;
            add.x = dbs[0][D][d2][wi]   + dbs[1][D][d2][wi]
                  + dbs[2][D][d2][wi]   + dbs[3][D][d2][wi];
            add.y = dbs[0][D][d2][wi+1] + dbs[1][D][d2][wi+1]
                  + dbs[2][D][d2][wi+1] + dbs[3][D][d2][wi+1];
            float2* bp = (float2*)&bws[((size_t)bb*64 + Dd)*HW + (size_t)h0*WOUT + w];
            if (MODE != 0) { float2 old = *bp; add.x += old.x; add.y += old.y; }
            *bp = add;
            ez = expf(add.x) + expf(add.y);   // same values later read as cms
        }
        #pragma unroll
        for (int off = 1; off < 32; off <<= 1) ez += __shfl_xor(ez, off);
        if ((t & 31) == 0)
            Zp[((size_t)bb*8 + D)*BLK_PER_B + h0*12 + wx] = ez;
    }
}

// ---------------------------------------------------------------------------
// Implicit-GEMM MFMA conv + fused routing.
// Block: (wx,h0,bb) -> 1 batch x 8 D x 1 h-row x 8 consecutive w; M=64, N=256.
// NOTE (r7): MFMA + in-register epilogue verified element-exact vs fp32.
// Do NOT reintroduce an LDS u_tile round-trip (rounds 4-6 corruption).
// r9: spatial 1x8 tiling for HBM line efficiency.
// r11: AC=1 stores the block's bf16 a_hi tile (21.5KB) to workspace; AC=2
//      replaces patch-staging+im2col with a coalesced float4 stream of the
//      cached tile — bitwise-identical MFMA inputs, ~1/3 the VALU work.
//      Z partials to per-block slots (no atomics; see zreduce note).
// ---------------------------------------------------------------------------
template<int MODE, int AC>
__global__ __launch_bounds__(256, 2) void conv_mfma_route(
    const float* __restrict__ x,
    const ushort* __restrict__ w_hi, const ushort* __restrict__ w_lo,
    float* __restrict__ bws, const float* __restrict__ Z,
    float* __restrict__ Zp, float* __restrict__ out, float* __restrict__ Ac)
{
    const int t  = threadIdx.x;
    const int wx = blockIdx.x, h0 = blockIdx.y, bb = blockIdx.z;
    const int w0 = wx*8;
    const size_t blk = ((size_t)bb*94 + h0)*12 + wx;

    __shared__ __align__(16) ushort a_hi[64][APAD];  // 21504 B (all phases)
    __shared__ float  cms[64][8];                    // 2048 B
    __shared__ float  invZ[8];
    __shared__ union {                               // 15360 B, lifetime-disjoint
        float patch[CIN][DDEP][3][10];               //   phases 0-1 (AC != 2)
        struct { float n2s[4][8][8];                 //   epilogue (MODE 0/1)
                 float dbs[4][8][8][8]; } ep;
        float sout[256][8];                          //   epilogue (MODE 2)
    } ov;

    // ---- phase 0: c-coeffs ----
    if (MODE != 0) {
        if (t < 8) invZ[t] = 1.0f / Z[(MODE == 2 ? 64 : 0) + bb*8 + t];
        for (int v = t; v < 512; v += 256) {
            int Dd = v >> 3, wi = v & 7;
            int w = w0 + wi;
            float bv = (w < WOUT) ? bws[((size_t)bb*64 + Dd)*HW + (size_t)h0*WOUT + w] : 0.f;
            cms[Dd][wi] = expf(bv);
        }
    }

    if (AC == 2) {
        // ---- cached A: stream 21.5KB coalesced into LDS ----
        const float4* src = (const float4*)Ac + blk*A_TILE_V4;
        float4* dst = (float4*)&a_hi[0][0];
        for (int i = t; i < A_TILE_V4; i += 256) dst[i] = src[i];
        __syncthreads();
    } else {
        // ---- phase 0b: stage x patch ----
        for (int i = t; i < CIN*DDEP*3*10; i += 256) {
            int ci = i / 240, rem = i - ci*240;
            int D  = rem / 30, rem2 = rem - D*30;
            int kh = rem2 / 10, col = rem2 - kh*10;
            int xc = w0 + col; if (xc > 95) xc = 95;   // clamp: garbage feeds only invalid sites
            ov.patch[ci][D][kh][col] =
                x[(((size_t)(bb*CIN + ci)*DDEP + D)*HIN + (h0+kh))*WIN + xc];
        }
        __syncthreads();

        // ---- phase 1: im2col -> bf16 A (uint stores; thread = site x kgroup) ----
        {
            const int site = t >> 2, kg = t & 3;     // site = D*8 + wi
            const int D = site >> 3, wi = site & 7;
            #pragma unroll
            for (int u2 = 0; u2 < 18; ++u2) {
                int k0 = kg*36 + u2*2;
                int ci0 = k0/9, r0 = k0 - ci0*9, kh0 = r0/3, kw0 = r0 - kh0*3;
                int k1 = k0 + 1;
                int ci1 = k1/9, r1 = k1 - ci1*9, kh1 = r1/3, kw1 = r1 - kh1*3;
                unsigned lo = f2bf(ov.patch[ci0][D][kh0][wi+kw0]);
                unsigned hi = f2bf(ov.patch[ci1][D][kh1][wi+kw1]);
                *(unsigned*)&a_hi[site][k0] = lo | (hi << 16);
            }
            if (t < 64) {
                #pragma unroll
                for (int kk = KTOT; kk < KTILES*32; kk += 2)
                    *(unsigned*)&a_hi[t][kk] = 0u;
            }
        }
        __syncthreads();
    }

    // ---- phase 2: MFMA K-loop ----
    const int wv = t >> 6, lane = t & 63;
    const int m16 = lane & 15, quad = lane >> 4;
    f32x4 acc[4][4];
    #pragma unroll
    for (int mt = 0; mt < 4; ++mt)
        #pragma unroll
        for (int nt = 0; nt < 4; ++nt)
            acc[mt][nt] = (f32x4){0.f, 0.f, 0.f, 0.f};

    #pragma unroll
    for (int kt = 0; kt < KTILES; ++kt) {
        bf16x8 ah[4];
        #pragma unroll
        for (int mt = 0; mt < 4; ++mt)
            ah[mt] = *(const bf16x8*)&a_hi[mt*16 + m16][kt*32 + quad*8];
        #pragma unroll
        for (int nt = 0; nt < 4; ++nt) {
            size_t off = (((size_t)kt*16 + (wv*4 + nt))*64 + lane)*8;
            bf16x8 bh = *(const bf16x8*)&w_hi[off];
            bf16x8 bl = *(const bf16x8*)&w_lo[off];
            #pragma unroll
            for (int mt = 0; mt < 4; ++mt) {
                acc[mt][nt] = __builtin_amdgcn_mfma_f32_16x16x32_bf16(ah[mt], bh, acc[mt][nt], 0, 0, 0);
                acc[mt][nt] = __builtin_amdgcn_mfma_f32_16x16x32_bf16(ah[mt], bl, acc[mt][nt], 0, 0, 0);
            }
        }
    }

    // ---- A-tile spill (fire-and-forget coalesced stores) ----
    if (AC == 1) {
        float4* dst = (float4*)Ac + blk*A_TILE_V4;
        const float4* src = (const float4*)&a_hi[0][0];
        for (int i = t; i < A_TILE_V4; i += 256) dst[i] = src[i];
    }

    // ---- phase 3: in-register epilogue ----
    routing_epilogue<MODE>(acc, t, wx, h0, bb, cms, invZ,
                           ov.ep.n2s, ov.ep.dbs, ov.sout, bws, Zp, out);
}

// ---------------------------------------------------------------------------
extern "C" void kernel_launch(void* const* d_in, const int* in_sizes, int n_in,
                              void* d_out, int out_size, void* d_ws, size_t ws_size,
                              hipStream_t stream)
{
    (void)in_sizes; (void)n_in; (void)out_size;
    const float* x     = (const float*)d_in[0];
    const float* wconv = (const float*)d_in[1];
    float* out = (float*)d_out;

    float*  bws  = (float*)d_ws;
    float*  Z    = bws + B_ELEMS;            // Z1 = Z[0..63], Z2 = Z[64..127]
    float*  Zp   = Z + 128;                  // 64*1128 per-block partials
    ushort* w_hi = (ushort*)(Zp + 64*BLK_PER_B);
    ushort* w_lo = w_hi + WFRAG_ELEMS;
    size_t  base = (size_t)((char*)(w_lo + WFRAG_ELEMS) - (char*)d_ws);
    size_t  aoff = (base + 255) & ~(size_t)255;
    float*  Ac   = (float*)((char*)d_ws + aoff);
    const bool big = ws_size >= aoff + AC_BYTES;   // ~213 MB for A-cache

    const dim3 grid(12, 94, 8);
    build_wfrag<<<dim3(16, KTILES), 64, 0, stream>>>(wconv, w_hi, w_lo);
    if (big) {
        conv_mfma_route<0, 1><<<grid, 256, 0, stream>>>(x, w_hi, w_lo, bws, Z, Zp, out, Ac);
        zreduce<<<64, 256, 0, stream>>>(Zp, Z, 0);
        conv_mfma_route<1, 2><<<grid, 256, 0, stream>>>(x, w_hi, w_lo, bws, Z, Zp, out, Ac);
        zreduce<<<64, 256, 0, stream>>>(Zp, Z, 64);
        conv_mfma_route<2, 2><<<grid, 256, 0, stream>>>(x, w_hi, w_lo, bws, Z, Zp, out, Ac);
    } else {
        // workspace too small for A-cache: recompute im2col each pass
        conv_mfma_route<0, 0><<<grid, 256, 0, stream>>>(x, w_hi, w_lo, bws, Z, Zp, out, nullptr);
        zreduce<<<64, 256, 0, stream>>>(Zp, Z, 0);
        conv_mfma_route<1, 0><<<grid, 256, 0, stream>>>(x, w_hi, w_lo, bws, Z, Zp, out, nullptr);
        zreduce<<<64, 256, 0, stream>>>(Zp, Z, 64);
        conv_mfma_route<2, 0><<<grid, 256, 0, stream>>>(x, w_hi, w_lo, bws, Z, Zp, out, nullptr);
    }
}

// Round 3
// 591.991 us; speedup vs baseline: 1.7766x; 1.0051x over previous
//
#include <hip/hip_runtime.h>
#include <math.h>

#define CIN   16
#define DDEP  8      // conv depth (routing "D")
#define HIN   96
#define WIN   96
#define HOUT  94
#define WOUT  94
#define HW    (HOUT*WOUT)        // 8836
#define CH    256                 // out channels = c*8+d
#define DCAP  8
#define KTOT  (CIN*9)             // 144
#define KTILES 5                  // K padded to 160
#define APAD  168                 // A row stride (bf16 elems)
#define EPSQ  1e-8f

#define B_ELEMS ((size_t)8*DDEP*DCAP*HW)          // 4,524,032 floats
#define WFRAG_ELEMS ((size_t)KTILES*16*64*8)      // 40,960 per half
#define BLK_PER_B (94*12)                         // 1128 spatial blocks/batch
#define NBLK ((size_t)8*BLK_PER_B)                // 9024 blocks
#define A_TILE_BYTES ((size_t)64*APAD*2)          // 21504 B per block
#define A_TILE_V4 (A_TILE_BYTES/16)               // 1344 float4 per block
#define AC_BYTES (NBLK*A_TILE_BYTES)              // 194,052,096 B
#define VSITES (DCAP*HW)                          // 70,688 sites per batch
#define NBLK2  277                                // ceil(70688/256)
#define G_BYTES ((size_t)8*VSITES*36*4)           // 81,432,576 B

typedef __attribute__((ext_vector_type(8))) short bf16x8;
typedef __attribute__((ext_vector_type(4))) float f32x4;

// explicit RNE float->bf16 bit conversion
__device__ __forceinline__ ushort f2bf(float f) {
    unsigned u = __float_as_uint(f);
    return (ushort)((u + 0x7FFFu + ((u >> 16) & 1u)) >> 16);
}
__device__ __forceinline__ float bf2f(ushort h) {
    return __uint_as_float(((unsigned)h) << 16);
}

// ---------------------------------------------------------------------------
// W -> MFMA B-fragment order, hi/lo split. frag[kt][nt][lane][j] = W[k][n],
// k = kt*32 + (lane>>4)*8 + j (0 for k>=144), n = nt*16 + (lane&15).
// ---------------------------------------------------------------------------
__global__ __launch_bounds__(64) void build_wfrag(
    const float* __restrict__ w, ushort* __restrict__ w_hi, ushort* __restrict__ w_lo)
{
    const int lane = threadIdx.x;
    const int nt = blockIdx.x, kt = blockIdx.y;
    const int n  = nt*16 + (lane & 15);
    const int kb = kt*32 + (lane >> 4)*8;
    size_t off = (((size_t)kt*16 + nt)*64 + lane)*8;
    for (int j = 0; j < 8; ++j) {
        int k = kb + j;
        float v = (k < KTOT) ? w[(size_t)n*KTOT + k] : 0.f;
        ushort hi = f2bf(v);
        float  r  = v - bf2f(hi);
        ushort lo = f2bf(r);
        w_hi[off + j] = hi; w_lo[off + j] = lo;
    }
}

// ---------------------------------------------------------------------------
// Z reduce from contention-free per-block partials (r10 lesson: NEVER funnel
// per-block Z through same-address device atomics — 72k RMWs on 8 lines
// serialized ~+120us/pass). count = slots per (bb,D) bin.
// ---------------------------------------------------------------------------
__global__ __launch_bounds__(256) void zreduce(
    const float* __restrict__ Zp, float* __restrict__ Z, int dst, int count)
{
    const int bd = blockIdx.x;
    const float* p = Zp + (size_t)bd * count;
    float s = 0.f;
    for (int i = threadIdx.x; i < count; i += 256) s += p[i];
    #pragma unroll
    for (int off = 1; off < 64; off <<= 1) s += __shfl_xor(s, off);
    __shared__ float ps[4];
    if ((threadIdx.x & 63) == 0) ps[threadIdx.x >> 6] = s;
    __syncthreads();
    if (threadIdx.x == 0) Z[dst + bd] = ps[0] + ps[1] + ps[2] + ps[3];
}

// ---------------------------------------------------------------------------
// Shared routing epilogue (phase 3). acc[mt][nt][r]:
//   m = mt*16 + quad*4 + r -> D = mt*2 + (quad>>1), wi = (quad&1)*4 + r;
//   ch = wv*64 + nt*16 + m16; d = m16&7.
// MODE 0: iter1 (uniform c), writes b + per-block Z1 partial.
// MODE 1: iter2 full path (fallback tier only), b += db, Z2 partial.
// MODE 2: writes s.
// NOTE (r7): epilogue verified element-exact; keep the math/order unchanged.
// ---------------------------------------------------------------------------
template<int MODE>
__device__ __forceinline__ void routing_epilogue(
    const f32x4 (&acc)[4][4], const int t, const int wx, const int h0, const int bb,
    const float (*cms)[8], const float* invZ,
    float (*n2s)[8][8], float (*dbs)[8][8][8], float (*sout)[8],
    float* __restrict__ bws, float* __restrict__ Zp, float* __restrict__ out)
{
    const int w0 = wx*8;
    const int wv = t >> 6, lane = t & 63;
    const int m16 = lane & 15, quad = lane >> 4;
    const int d   = m16 & 7;
    const int Dq  = quad >> 1;      // D parity bit (lane bit5)
    const int wih = quad & 1;       // wi half (lane bit4)

    // sv[nt][r] = sum_D cm(D,d,wi)*u(D,...): reg-sum over mt + shfl_xor(32)
    float svv[4][4];
    {
        float cmw[4][4];
        if (MODE == 0) {
            const float inv = 1.0f / (float)(DCAP * HW);
            #pragma unroll
            for (int mt = 0; mt < 4; ++mt)
                #pragma unroll
                for (int r = 0; r < 4; ++r) cmw[mt][r] = inv;
        } else {
            #pragma unroll
            for (int mt = 0; mt < 4; ++mt) {
                int D = mt*2 + Dq;
                float iz = invZ[D];
                #pragma unroll
                for (int r = 0; r < 4; ++r) cmw[mt][r] = cms[D*8 + d][wih*4 + r] * iz;
            }
        }
        #pragma unroll
        for (int nt = 0; nt < 4; ++nt)
            #pragma unroll
            for (int r = 0; r < 4; ++r) {
                float partial = 0.f;
                #pragma unroll
                for (int mt = 0; mt < 4; ++mt) partial += cmw[mt][r]*acc[mt][nt][r];
                partial += __shfl_xor(partial, 32);
                svv[nt][r] = partial;   // uniform in lane bit5
            }
    }

    if (MODE == 2) {
        if (quad < 2) {   // one Dq copy per (wih, m16, nt)
            #pragma unroll
            for (int nt = 0; nt < 4; ++nt) {
                int ch = wv*64 + nt*16 + m16;
                #pragma unroll
                for (int r = 0; r < 4; ++r) sout[ch][wih*4 + r] = svv[nt][r];
            }
        }
        __syncthreads();
        for (int i = t; i < 1024; i += 256) {
            int c2 = i >> 2, wip = i & 3;
            int w = w0 + wip*2;
            if (w + 1 < WOUT) {
                float2 v2 = { sout[c2][wip*2], sout[c2][wip*2 + 1] };
                *(float2*)&out[((size_t)bb*CH + c2)*HW + (size_t)h0*WOUT + w] = v2;
            }
        }
        return;
    }

    // n2(d,wi) = sum_c sv^2 : reg-sum over nt + shfl_xor(8) + cross-wave LDS
    float p2[4];
    #pragma unroll
    for (int r = 0; r < 4; ++r) {
        float s2 = 0.f;
        #pragma unroll
        for (int nt = 0; nt < 4; ++nt) s2 += svv[nt][r]*svv[nt][r];
        p2[r] = s2;
    }
    #pragma unroll
    for (int r = 0; r < 4; ++r) p2[r] += __shfl_xor(p2[r], 8);
    if (quad < 2 && m16 < 8) {
        #pragma unroll
        for (int r = 0; r < 4; ++r) n2s[wv][m16][quad*4 + r] = p2[r];
    }
    __syncthreads();
    float fac[4];
    #pragma unroll
    for (int r = 0; r < 4; ++r) {
        int wi = wih*4 + r;
        float n2 = n2s[0][d][wi] + n2s[1][d][wi] + n2s[2][d][wi] + n2s[3][d][wi];
        fac[r] = (n2 / (1.f + n2)) / sqrtf(n2 + EPSQ);
    }
    // db(D,d,wi) = sum_c u*v : reg-sum over nt + shfl_xor(8) + cross-wave LDS
    float qv[4][4];
    #pragma unroll
    for (int mt = 0; mt < 4; ++mt)
        #pragma unroll
        for (int r = 0; r < 4; ++r) {
            float sum = 0.f;
            #pragma unroll
            for (int nt = 0; nt < 4; ++nt)
                sum += acc[mt][nt][r] * (svv[nt][r] * fac[r]);
            qv[mt][r] = sum;
        }
    #pragma unroll
    for (int mt = 0; mt < 4; ++mt)
        #pragma unroll
        for (int r = 0; r < 4; ++r) qv[mt][r] += __shfl_xor(qv[mt][r], 8);
    if (m16 < 8) {
        #pragma unroll
        for (int mt = 0; mt < 4; ++mt) {
            int D = mt*2 + Dq;
            #pragma unroll
            for (int r = 0; r < 4; ++r) dbs[wv][D][m16][wih*4 + r] = qv[mt][r];
        }
    }
    __syncthreads();
    // b write: 64 (D,d) x 8 wi, float2 runs + per-block Z partial
    {
        int Dd = t >> 2, wip = t & 3;
        int D = Dd >> 3, d2 = Dd & 7;   // D = t>>5, uniform per 32-lane group
        int w = w0 + wip*2;
        float ez = 0.f;
        if (w + 1 < WOUT) {
            int wi = wip*2;
            float2 add;
            add.x = dbs[0][D][d2][wi]   + dbs[1][D][d2][wi]
                  + dbs[2][D][d2][wi]   + dbs[3][D][d2][wi];
            add.y = dbs[0][D][d2][wi+1] + dbs[1][D][d2][wi+1]
                  + dbs[2][D][d2][wi+1] + dbs[3][D][d2][wi+1];
            float2* bp = (float2*)&bws[((size_t)bb*64 + Dd)*HW + (size_t)h0*WOUT + w];
            if (MODE != 0) { float2 old = *bp; add.x += old.x; add.y += old.y; }
            *bp = add;
            ez = expf(add.x) + expf(add.y);   // same values later read as cms
        }
        #pragma unroll
        for (int off = 1; off < 32; off <<= 1) ez += __shfl_xor(ez, off);
        if ((t & 31) == 0)
            Zp[((size_t)bb*8 + D)*BLK_PER_B + h0*12 + wx] = ez;
    }
}

// ---------------------------------------------------------------------------
// Implicit-GEMM MFMA conv + fused routing.
// Block: (wx,h0,bb) -> 1 batch x 8 D x 1 h-row x 8 consecutive w; M=64, N=256.
// NOTE (r7): MFMA + in-register epilogue verified element-exact vs fp32.
// r11: AC=1 stores bf16 a_hi tile to ws; AC=2 streams it back (bitwise-same
//      MFMA inputs). r12: GW=true computes the per-site 8x8 Gram matrix
//      G_DD' = sum_c u_cD*u_cD' from live acc registers and stores 36 sym
//      entries/site -> iter2 becomes the tiny gram_route kernel (conv pass
//      eliminated). G uses exact fp32 products of the same acc values.
// ---------------------------------------------------------------------------
template<int MODE, int AC, bool GW>
__global__ __launch_bounds__(256, 2) void conv_mfma_route(
    const float* __restrict__ x,
    const ushort* __restrict__ w_hi, const ushort* __restrict__ w_lo,
    float* __restrict__ bws, const float* __restrict__ Z,
    float* __restrict__ Zp, float* __restrict__ out,
    float* __restrict__ Ac, float* __restrict__ Gm)
{
    const int t  = threadIdx.x;
    const int wx = blockIdx.x, h0 = blockIdx.y, bb = blockIdx.z;
    const int w0 = wx*8;
    const size_t blk = ((size_t)bb*94 + h0)*12 + wx;

    __shared__ __align__(16) ushort a_hi[64][APAD];  // 21504 B (all phases)
    __shared__ float  cms[64][8];                    // 2048 B
    __shared__ float  invZ[8];
    __shared__ union {                               // 15360 B, lifetime-disjoint
        float patch[CIN][DDEP][3][10];               //   phases 0-1 (AC != 2)
        struct { float n2s[4][8][8];                 //   epilogue (MODE 0/1)
                 float dbs[4][8][8][8]; } ep;
        float sout[256][8];                          //   epilogue (MODE 2)
        float gst[4][16][36];                        //   G staging (GW, post-ep)
    } ov;

    // ---- phase 0: c-coeffs ----
    if (MODE != 0) {
        if (t < 8) invZ[t] = 1.0f / Z[(MODE == 2 ? 64 : 0) + bb*8 + t];
        for (int v = t; v < 512; v += 256) {
            int Dd = v >> 3, wi = v & 7;
            int w = w0 + wi;
            float bv = (w < WOUT) ? bws[((size_t)bb*64 + Dd)*HW + (size_t)h0*WOUT + w] : 0.f;
            cms[Dd][wi] = expf(bv);
        }
    }

    if (AC == 2) {
        // ---- cached A: stream 21.5KB coalesced into LDS ----
        const float4* src = (const float4*)Ac + blk*A_TILE_V4;
        float4* dst = (float4*)&a_hi[0][0];
        for (int i = t; i < A_TILE_V4; i += 256) dst[i] = src[i];
        __syncthreads();
    } else {
        // ---- phase 0b: stage x patch ----
        for (int i = t; i < CIN*DDEP*3*10; i += 256) {
            int ci = i / 240, rem = i - ci*240;
            int D  = rem / 30, rem2 = rem - D*30;
            int kh = rem2 / 10, col = rem2 - kh*10;
            int xc = w0 + col; if (xc > 95) xc = 95;   // clamp: garbage feeds only invalid sites
            ov.patch[ci][D][kh][col] =
                x[(((size_t)(bb*CIN + ci)*DDEP + D)*HIN + (h0+kh))*WIN + xc];
        }
        __syncthreads();

        // ---- phase 1: im2col -> bf16 A (uint stores; thread = site x kgroup) ----
        {
            const int site = t >> 2, kg = t & 3;     // site = D*8 + wi
            const int D = site >> 3, wi = site & 7;
            #pragma unroll
            for (int u2 = 0; u2 < 18; ++u2) {
                int k0 = kg*36 + u2*2;
                int ci0 = k0/9, r0 = k0 - ci0*9, kh0 = r0/3, kw0 = r0 - kh0*3;
                int k1 = k0 + 1;
                int ci1 = k1/9, r1 = k1 - ci1*9, kh1 = r1/3, kw1 = r1 - kh1*3;
                unsigned lo = f2bf(ov.patch[ci0][D][kh0][wi+kw0]);
                unsigned hi = f2bf(ov.patch[ci1][D][kh1][wi+kw1]);
                *(unsigned*)&a_hi[site][k0] = lo | (hi << 16);
            }
            if (t < 64) {
                #pragma unroll
                for (int kk = KTOT; kk < KTILES*32; kk += 2)
                    *(unsigned*)&a_hi[t][kk] = 0u;
            }
        }
        __syncthreads();
    }

    // ---- phase 2: MFMA K-loop ----
    const int wv = t >> 6, lane = t & 63;
    const int m16 = lane & 15, quad = lane >> 4;
    const int Dq = quad >> 1, wih = quad & 1;
    f32x4 acc[4][4];
    #pragma unroll
    for (int mt = 0; mt < 4; ++mt)
        #pragma unroll
        for (int nt = 0; nt < 4; ++nt)
            acc[mt][nt] = (f32x4){0.f, 0.f, 0.f, 0.f};

    #pragma unroll
    for (int kt = 0; kt < KTILES; ++kt) {
        bf16x8 ah[4];
        #pragma unroll
        for (int mt = 0; mt < 4; ++mt)
            ah[mt] = *(const bf16x8*)&a_hi[mt*16 + m16][kt*32 + quad*8];
        #pragma unroll
        for (int nt = 0; nt < 4; ++nt) {
            size_t off = (((size_t)kt*16 + (wv*4 + nt))*64 + lane)*8;
            bf16x8 bh = *(const bf16x8*)&w_hi[off];
            bf16x8 bl = *(const bf16x8*)&w_lo[off];
            #pragma unroll
            for (int mt = 0; mt < 4; ++mt) {
                acc[mt][nt] = __builtin_amdgcn_mfma_f32_16x16x32_bf16(ah[mt], bh, acc[mt][nt], 0, 0, 0);
                acc[mt][nt] = __builtin_amdgcn_mfma_f32_16x16x32_bf16(ah[mt], bl, acc[mt][nt], 0, 0, 0);
            }
        }
    }

    // ---- A-tile spill (fire-and-forget coalesced stores) ----
    if (AC == 1) {
        float4* dst = (float4*)Ac + blk*A_TILE_V4;
        const float4* src = (const float4*)&a_hi[0][0];
        for (int i = t; i < A_TILE_V4; i += 256) dst[i] = src[i];
    }

    // ---- phase 3: in-register epilogue ----
    routing_epilogue<MODE>(acc, t, wx, h0, bb, cms, invZ,
                           ov.ep.n2s, ov.ep.dbs, ov.sout, bws, Zp, out);

    // ---- phase 4 (GW): Gram matrix G_DD'(d,wi) = sum_c u_cD*u_cD' ----
    // Each thread holds 4 D's (its Dq half); partner lane^32 has the other 4
    // (same ch, same wi). r-split dedup: Dq==(r>>1) half accumulates for r.
    // Reduce c over: nt (reg loop), c3=m16>>3 (shfl_xor 8), wv (LDS stage).
    if constexpr (GW) {
        const int c3 = m16 >> 3;
        const int dL = m16 & 7;
        __syncthreads();   // epilogue waves done reading ov.ep before gst reuse
        #pragma unroll
        for (int r = 0; r < 4; ++r) {
            const int rq = r >> 1;          // assigned Dq for this r
            float G36[36];
            #pragma unroll
            for (int j = 0; j < 36; ++j) G36[j] = 0.f;
            #pragma unroll
            for (int nt = 0; nt < 4; ++nt) {
                float u8[8];
                #pragma unroll
                for (int mt = 0; mt < 4; ++mt) {
                    float own = acc[mt][nt][r];
                    float oth = __shfl_xor(own, 32);   // all lanes participate
                    if (Dq == 0) { u8[mt*2]   = own; u8[mt*2+1] = oth; }
                    else         { u8[mt*2+1] = own; u8[mt*2]   = oth; }
                }
                if (Dq == rq) {
                    int idx = 0;
                    #pragma unroll
                    for (int D = 0; D < 8; ++D)
                        #pragma unroll
                        for (int Dp = D; Dp < 8; ++Dp) {
                            G36[idx] += u8[D]*u8[Dp];
                            ++idx;
                        }
                }
            }
            if (Dq == rq) {   // xor-8 partners share Dq; half-wave uniform
                #pragma unroll
                for (int j = 0; j < 36; ++j) G36[j] += __shfl_xor(G36[j], 8);
                if (c3 == 0) {
                    #pragma unroll
                    for (int j = 0; j < 36; ++j) ov.gst[wv][dL*2 + wih][j] = G36[j];
                }
            }
            __syncthreads();
            // cross-wave sum + global write: 16 sites x 36, 144B runs per site
            for (int idx2 = t; idx2 < 16*36; idx2 += 256) {
                int sidx = idx2 / 36, j = idx2 - sidx*36;
                int dd = sidx >> 1, wh = sidx & 1;
                int w = w0 + wh*4 + r;
                if (w < WOUT) {
                    float gv = ov.gst[0][sidx][j] + ov.gst[1][sidx][j]
                             + ov.gst[2][sidx][j] + ov.gst[3][sidx][j];
                    size_t gsite = ((size_t)(bb*DCAP + dd)*HOUT + h0)*WOUT + w;
                    Gm[gsite*36 + j] = gv;
                }
            }
            __syncthreads();   // before next r overwrites gst
        }
    }
}

// ---------------------------------------------------------------------------
// r12: routing iteration 2 from the Gram matrix. Per site (bb,d,h,w):
//   cm_D = exp(b1_D)/Z1_D;  t_D = (G cm)_D;  n2 = cm^T G cm;
//   fac = (n2/(1+n2))/sqrt(n2+eps);  b2 = b1 + fac*t;  Z2 partials to Zp.
// Pure streaming: ~118 MB total vs a full 170us conv pass.
// Blocks are padded per-batch (NBLK2*256 >= VSITES) so each block has one bb.
// ---------------------------------------------------------------------------
__global__ __launch_bounds__(256) void gram_route(
    const float* __restrict__ Gm, float* __restrict__ bws,
    const float* __restrict__ Z, float* __restrict__ Zp)
{
    const int k = blockIdx.x, bb = blockIdx.y;
    const int t = threadIdx.x;
    const int local = k*256 + t;
    const bool valid = local < VSITES;
    float ez[8];
    #pragma unroll
    for (int D = 0; D < 8; ++D) ez[D] = 0.f;
    if (valid) {
        const int d  = local / HW;
        const int r2 = local - d*HW;
        float bv[8], cm[8];
        #pragma unroll
        for (int D = 0; D < 8; ++D) {
            bv[D] = bws[((size_t)(bb*64 + D*8 + d))*HW + r2];
            cm[D] = expf(bv[D]) * (1.0f / Z[bb*8 + D]);
        }
        float g[36];
        const float4* gp = (const float4*)(Gm + (size_t)(bb*VSITES + local)*36);
        #pragma unroll
        for (int q = 0; q < 9; ++q) {
            float4 v = gp[q];
            g[q*4+0] = v.x; g[q*4+1] = v.y; g[q*4+2] = v.z; g[q*4+3] = v.w;
        }
        float tD[8];
        #pragma unroll
        for (int D = 0; D < 8; ++D) tD[D] = 0.f;
        {
            int idx = 0;
            #pragma unroll
            for (int D = 0; D < 8; ++D)
                #pragma unroll
                for (int Dp = D; Dp < 8; ++Dp) {
                    float gv = g[idx]; ++idx;
                    tD[D] += cm[Dp] * gv;
                    if (Dp != D) tD[Dp] += cm[D] * gv;
                }
        }
        float n2 = 0.f;
        #pragma unroll
        for (int D = 0; D < 8; ++D) n2 += cm[D] * tD[D];
        float fac = (n2 / (1.f + n2)) / sqrtf(n2 + EPSQ);
        #pragma unroll
        for (int D = 0; D < 8; ++D) {
            float nb = bv[D] + fac * tD[D];
            bws[((size_t)(bb*64 + D*8 + d))*HW + r2] = nb;
            ez[D] = expf(nb);
        }
    }
    // block-reduce 8 per-D sums -> contention-free Zp slot
    #pragma unroll
    for (int D = 0; D < 8; ++D)
        #pragma unroll
        for (int off = 1; off < 64; off <<= 1) ez[D] += __shfl_xor(ez[D], off);
    __shared__ float ps[4][8];
    if ((t & 63) == 0) {
        #pragma unroll
        for (int D = 0; D < 8; ++D) ps[t >> 6][D] = ez[D];
    }
    __syncthreads();
    if (t < 8)
        Zp[((size_t)bb*8 + t)*NBLK2 + k] = ps[0][t] + ps[1][t] + ps[2][t] + ps[3][t];
}

// ---------------------------------------------------------------------------
extern "C" void kernel_launch(void* const* d_in, const int* in_sizes, int n_in,
                              void* d_out, int out_size, void* d_ws, size_t ws_size,
                              hipStream_t stream)
{
    (void)in_sizes; (void)n_in; (void)out_size;
    const float* x     = (const float*)d_in[0];
    const float* wconv = (const float*)d_in[1];
    float* out = (float*)d_out;

    float*  bws  = (float*)d_ws;
    float*  Z    = bws + B_ELEMS;            // Z1 = Z[0..63], Z2 = Z[64..127]
    float*  Zp   = Z + 128;                  // 64*1128 partials (reused by gram)
    ushort* w_hi = (ushort*)(Zp + 64*BLK_PER_B);
    ushort* w_lo = w_hi + WFRAG_ELEMS;
    size_t  base = (size_t)((char*)(w_lo + WFRAG_ELEMS) - (char*)d_ws);
    size_t  goff = (base + 255) & ~(size_t)255;
    float*  Gm   = (float*)((char*)d_ws + goff);
    size_t  aoff = (goff + G_BYTES + 255) & ~(size_t)255;
    float*  Ac   = (float*)((char*)d_ws + aoff);
    const bool haveG = ws_size >= goff + G_BYTES;          // ~100 MB
    const bool haveA = ws_size >= aoff + AC_BYTES;         // ~294 MB

    const dim3 grid(12, 94, 8);
    build_wfrag<<<dim3(16, KTILES), 64, 0, stream>>>(wconv, w_hi, w_lo);
    if (haveG && haveA) {
        conv_mfma_route<0, 1, true ><<<grid, 256, 0, stream>>>(x, w_hi, w_lo, bws, Z, Zp, out, Ac, Gm);
        zreduce<<<64, 256, 0, stream>>>(Zp, Z, 0, BLK_PER_B);
        gram_route<<<dim3(NBLK2, 8), 256, 0, stream>>>(Gm, bws, Z, Zp);
        zreduce<<<64, 256, 0, stream>>>(Zp, Z, 64, NBLK2);
        conv_mfma_route<2, 2, false><<<grid, 256, 0, stream>>>(x, w_hi, w_lo, bws, Z, Zp, out, Ac, nullptr);
    } else if (haveG) {
        conv_mfma_route<0, 0, true ><<<grid, 256, 0, stream>>>(x, w_hi, w_lo, bws, Z, Zp, out, nullptr, Gm);
        zreduce<<<64, 256, 0, stream>>>(Zp, Z, 0, BLK_PER_B);
        gram_route<<<dim3(NBLK2, 8), 256, 0, stream>>>(Gm, bws, Z, Zp);
        zreduce<<<64, 256, 0, stream>>>(Zp, Z, 64, NBLK2);
        conv_mfma_route<2, 0, false><<<grid, 256, 0, stream>>>(x, w_hi, w_lo, bws, Z, Zp, out, nullptr, nullptr);
    } else {
        // minimal workspace: original 3-pass recompute
        conv_mfma_route<0, 0, false><<<grid, 256, 0, stream>>>(x, w_hi, w_lo, bws, Z, Zp, out, nullptr, nullptr);
        zreduce<<<64, 256, 0, stream>>>(Zp, Z, 0, BLK_PER_B);
        conv_mfma_route<1, 0, false><<<grid, 256, 0, stream>>>(x, w_hi, w_lo, bws, Z, Zp, out, nullptr, nullptr);
        zreduce<<<64, 256, 0, stream>>>(Zp, Z, 64, BLK_PER_B);
        conv_mfma_route<2, 0, false><<<grid, 256, 0, stream>>>(x, w_hi, w_lo, bws, Z, Zp, out, nullptr, nullptr);
    }
}